// Round 3
// baseline (231.784 us; speedup 1.0000x reference)
//
#include <hip/hip_runtime.h>
#include <hip/hip_bf16.h>

// Problem constants
#define BATCH  128
#define HWN    196          // (224/16)^2 patches per sample
#define HIDN   768
#define KN     768          // 3*16*16
#define IMGSZ  224
#define IMG2   (224*224)
#define MTOT   (BATCH*HWN)  // 25088 output rows

// GEMM tiling
#define BM 128
#define BN 128
#define BK 32
#define NT  (KN/BK)         // 24 K-steps (even -> clean 2-step pairing)
#define NBM (MTOT/BM)       // 196
#define NBN (HIDN/BN)       // 6
#define NWG (NBM*NBN)       // 1176 = 8 * 147 exactly -> bijective XCD swizzle
#define CPX (NWG/8)         // 147

typedef __attribute__((ext_vector_type(8))) short bf16x8;
typedef __attribute__((ext_vector_type(4))) float floatx4;

static __device__ __forceinline__ short f2bf(float f) {
    __hip_bfloat16 h = __float2bfloat16(f);   // RNE
    return __builtin_bit_cast(short, h);
}

static __device__ __forceinline__ bf16x8 cvt8v(float4 f0, float4 f1) {
    bf16x8 v;
    v[0]=f2bf(f0.x); v[1]=f2bf(f0.y); v[2]=f2bf(f0.z); v[3]=f2bf(f0.w);
    v[4]=f2bf(f1.x); v[5]=f2bf(f1.y); v[6]=f2bf(f1.z); v[7]=f2bf(f1.w);
    return v;
}

struct xs16 { float4 a, b, c, d; };   // 16 fp32 = one (row, 16-col) A source seg

// ---------------------------------------------------------------------------
// prep_W: fp32 -> bf16, 768*768 elems, 8 per thread. 288 blocks of 256. ~2 us.
// ---------------------------------------------------------------------------
__global__ __launch_bounds__(256)
void prep_W(const float* __restrict__ W, unsigned short* __restrict__ Wb)
{
    const int idx = blockIdx.x * 256 + threadIdx.x;   // < 73728
    float4 f0 = *(const float4*)(W + (size_t)idx * 8);
    float4 f1 = *(const float4*)(W + (size_t)idx * 8 + 4);
    *(bf16x8*)(Wb + (size_t)idx * 8) = cvt8v(f0, f1);
}

// ---------------------------------------------------------------------------
// gemm_fused v2b: C[r,n] = sum_k bf16(x_gathered)[r,k]*Wb[n,k] + bias[n]
// Structure (vs the 115us v1, which was latency-serialized):
//   * NO global_load_lds: B fragments load straight from L2-resident Wb into
//     registers (1-iter prefetch) -> no vmcnt(0) drain at barriers.
//   * As double-buffered (2 x 8 KB) -> ONE barrier/iter (lgkm-only drain).
//   * x gather register-prefetched 2 iterations deep (xq/xl rotation).
//   * K-loop = 12 iterations of an explicit 2-step pair; the LDS buffer index
//     is a macro LITERAL in each step -> static indexing without relying on
//     full unroll (rule #20 hardening; also ~2x smaller code than v2).
// LDS A layout: [128][32] bf16 rows (64 B); 16B-slot index XOR'd with
// ((row>>1)&1) on BOTH ds_write and fragment ds_read (involution) -> both
// sides at the 8-lanes-per-16B-slot b128 floor.
// ---------------------------------------------------------------------------
__global__ __launch_bounds__(256, 3)
void gemm_fused(const float* __restrict__ x, const int* __restrict__ perm,
                const unsigned short* __restrict__ Wb,
                const float* __restrict__ bias, float* __restrict__ out)
{
    __shared__ __align__(16) unsigned short As[2][BM * BK];  // 16 KB total

    const int tid = threadIdx.x;
    // XCD-bijective swizzle: 147 consecutive bm-major tiles per XCD, so the 6
    // bn-tiles of one bm-panel share that XCD's L2 (x-panel fetched ~once).
    const int wg  = blockIdx.x;
    const int lid = (wg & 7) * CPX + (wg >> 3);
    const int bm  = lid / NBN;
    const int bn  = lid - bm * NBN;

    // ---- A staging coords: thread owns (row = tid>>1, 16-col seg = tid&1)
    const int arow = tid >> 1;
    const int aseg = tid & 1;
    const int gr   = bm * BM + arow;
    const int b    = gr / HWN;
    const int p    = perm[gr];
    const int py   = p / 14, px = p - py * 14;
    const float* xbase = x + (size_t)b * 3 * IMG2
                           + (size_t)(py * 16) * IMGSZ + px * 16;
    const int axor  = ((arow >> 1) & 1) << 4;
    const int aoff0 = arow * 64 + ((aseg * 32     ) ^ axor);
    const int aoff1 = arow * 64 + ((aseg * 32 + 16) ^ axor);

    // ---- fragment coords
    const int lane = tid & 63;
    const int wave = tid >> 6;
    const int wm = (wave >> 1) * 64;
    const int wn = (wave & 1) * 64;
    const int lr = lane & 15;
    const int lq = lane >> 4;
    const int ard = (lq * 16) ^ (((lr >> 1) & 1) << 4);  // swizzled afrag k-byte

    // B fragment row pointers (L2-resident; 16 full cache lines per load instr)
    const unsigned short* wrow0 = Wb + (size_t)(bn * BN + wn +  0 + lr) * KN + lq * 8;
    const unsigned short* wrow1 = Wb + (size_t)(bn * BN + wn + 16 + lr) * KN + lq * 8;
    const unsigned short* wrow2 = Wb + (size_t)(bn * BN + wn + 32 + lr) * KN + lq * 8;
    const unsigned short* wrow3 = Wb + (size_t)(bn * BN + wn + 48 + lr) * KN + lq * 8;

    floatx4 acc[4][4] = {};

    auto loadx = [&](int t) -> xs16 {
        const int s = t * 2 + aseg;               // global 16-float seg id 0..47
        const float* src = xbase + (s >> 4) * IMG2 + (s & 15) * IMGSZ;
        xs16 r;
        r.a = *(const float4*)(src);
        r.b = *(const float4*)(src + 4);
        r.c = *(const float4*)(src + 8);
        r.d = *(const float4*)(src + 12);
        return r;
    };
    auto writea = [&](unsigned short* buf, const xs16& v) {
        *(bf16x8*)((char*)buf + aoff0) = cvt8v(v.a, v.b);
        *(bf16x8*)((char*)buf + aoff1) = cvt8v(v.c, v.d);
    };

    bf16x8 bfr0, bfr1, bfr2, bfr3;
    xs16 xq, xl;

    // ---- prologue: stage tile 0, prefetch tiles 1 & 2 (x) and tile 0 (B)
    xq = loadx(0);
    bfr0 = *(const bf16x8*)(wrow0);
    bfr1 = *(const bf16x8*)(wrow1);
    bfr2 = *(const bf16x8*)(wrow2);
    bfr3 = *(const bf16x8*)(wrow3);
    writea(As[0], xq);              // waits on xq only
    xq = loadx(1);
    xl = loadx(2);
    __syncthreads();                // As[0] visible (lgkm drain only)

    // One K-step. CUR/NXT are macro literals -> As indexing is fully static.
#define STEP(T, CUR, NXT)                                                     \
    do {                                                                      \
        const int t_ = (T);                                                   \
        if (t_ + 1 < NT) writea(As[NXT], xq);                                 \
        xq = xl;                                                              \
        if (t_ + 3 < NT) xl = loadx(t_ + 3);                                  \
        bf16x8 bnx0, bnx1, bnx2, bnx3;                                        \
        if (t_ + 1 < NT) {                                                    \
            bnx0 = *(const bf16x8*)(wrow0 + (t_ + 1) * BK);                   \
            bnx1 = *(const bf16x8*)(wrow1 + (t_ + 1) * BK);                   \
            bnx2 = *(const bf16x8*)(wrow2 + (t_ + 1) * BK);                   \
            bnx3 = *(const bf16x8*)(wrow3 + (t_ + 1) * BK);                   \
        }                                                                     \
        _Pragma("unroll")                                                     \
        for (int i = 0; i < 4; ++i) {                                         \
            const bf16x8 afrag = *(const bf16x8*)((const char*)As[CUR]        \
                                      + (wm + i * 16 + lr) * 64 + ard);       \
            acc[i][0] = __builtin_amdgcn_mfma_f32_16x16x32_bf16(afrag, bfr0, acc[i][0], 0, 0, 0); \
            acc[i][1] = __builtin_amdgcn_mfma_f32_16x16x32_bf16(afrag, bfr1, acc[i][1], 0, 0, 0); \
            acc[i][2] = __builtin_amdgcn_mfma_f32_16x16x32_bf16(afrag, bfr2, acc[i][2], 0, 0, 0); \
            acc[i][3] = __builtin_amdgcn_mfma_f32_16x16x32_bf16(afrag, bfr3, acc[i][3], 0, 0, 0); \
        }                                                                     \
        if (t_ + 1 < NT) {                                                    \
            bfr0 = bnx0; bfr1 = bnx1; bfr2 = bnx2; bfr3 = bnx3;               \
            __syncthreads();   /* As[CUR] reads done; As[NXT] visible */      \
        }                                                                     \
    } while (0)

    for (int tt = 0; tt < NT; tt += 2) {
        STEP(tt,     0, 1);
        STEP(tt + 1, 1, 0);
    }
#undef STEP

    // epilogue: bias + store (C/D: col = lane&15, row = quad*4 + reg)
    #pragma unroll
    for (int j = 0; j < 4; ++j) {
        const int gc = bn * BN + wn + j * 16 + lr;
        const float bv = bias[gc];
        #pragma unroll
        for (int i = 0; i < 4; ++i) {
            const int grow = bm * BM + wm + i * 16 + lq * 4;
            float* op = out + (size_t)grow * HIDN + gc;
            #pragma unroll
            for (int r = 0; r < 4; ++r)
                op[(size_t)r * HIDN] = acc[i][j][r] + bv;
        }
    }
}

extern "C" void kernel_launch(void* const* d_in, const int* in_sizes, int n_in,
                              void* d_out, int out_size, void* d_ws, size_t ws_size,
                              hipStream_t stream) {
    const float* x    = (const float*)d_in[0];
    const float* W    = (const float*)d_in[1];
    const float* bias = (const float*)d_in[2];
    const int*   perm = (const int*)d_in[3];
    float* out = (float*)d_out;

    // workspace: only Wb bf16 [768*768] (1.2 MB) — A is never materialized
    unsigned short* Wb = (unsigned short*)d_ws;

    prep_W<<<dim3(KN * HIDN / 8 / 256), dim3(256), 0, stream>>>(W, Wb);
    gemm_fused<<<dim3(NWG), dim3(256), 0, stream>>>(x, perm, Wb, bias, out);
}

// Round 4
// 218.272 us; speedup vs baseline: 1.0619x; 1.0619x over previous
//
#include <hip/hip_runtime.h>
#include <hip/hip_bf16.h>

// Problem constants
#define BATCH  128
#define HWN    196          // (224/16)^2 patches per sample
#define HIDN   768
#define KN     768          // 3*16*16
#define IMGSZ  224
#define IMG2   (224*224)
#define MTOT   (BATCH*HWN)  // 25088 rows

// GEMM tiling
#define BM 128
#define BN 128
#define BK 32
#define NT  (KN/BK)         // 24 K-steps (even -> clean 2-step pairing)
#define NBM (MTOT/BM)       // 196
#define NBN (HIDN/BN)       // 6
#define NWG (NBM*NBN)       // 1176 = 8 * 147 exactly -> bijective XCD swizzle
#define CPX (NWG/8)         // 147

typedef __attribute__((ext_vector_type(8))) short bf16x8;
typedef __attribute__((ext_vector_type(4))) float floatx4;
typedef __attribute__((ext_vector_type(4))) int   intx4;

static __device__ __forceinline__ short f2bf(float f) {
    __hip_bfloat16 h = __float2bfloat16(f);   // RNE
    return __builtin_bit_cast(short, h);
}

static __device__ __forceinline__ bf16x8 cvt8v(float4 f0, float4 f1) {
    bf16x8 v;
    v[0]=f2bf(f0.x); v[1]=f2bf(f0.y); v[2]=f2bf(f0.z); v[3]=f2bf(f0.w);
    v[4]=f2bf(f1.x); v[5]=f2bf(f1.y); v[6]=f2bf(f1.z); v[7]=f2bf(f1.w);
    return v;
}

struct xs16 { float4 a, b, c, d; };   // 16 fp32 = one (row, 16-col) A source seg

// ---------------------------------------------------------------------------
// prep_W: fp32 -> bf16, 768*768 elems, 8 per thread. 288 blocks of 256. ~2 us.
// ---------------------------------------------------------------------------
__global__ __launch_bounds__(256)
void prep_W(const float* __restrict__ W, unsigned short* __restrict__ Wb)
{
    const int idx = blockIdx.x * 256 + threadIdx.x;   // < 73728
    float4 f0 = *(const float4*)(W + (size_t)idx * 8);
    float4 f1 = *(const float4*)(W + (size_t)idx * 8 + 4);
    *(bf16x8*)(Wb + (size_t)idx * 8) = cvt8v(f0, f1);
}

// ---------------------------------------------------------------------------
// prep_inv: global inverse row map. shuffled[i,j] = enc[i, perm[i,j]]
//   => enc global row (i*196+p) must be stored at out row (i*196+j) where
//      p = perm[i*196+j].  invg[i*196+p] = i*196+j.  25088 thr = 98 blocks.
// ---------------------------------------------------------------------------
__global__ __launch_bounds__(256)
void prep_inv(const int* __restrict__ perm, int* __restrict__ invg)
{
    const int idx = blockIdx.x * 256 + threadIdx.x;   // < 25088 (98*256 exact)
    const int i = idx / HWN;
    const int p = perm[idx];
    invg[i * HWN + p] = idx;
}

// ---------------------------------------------------------------------------
// gemm_fused v3: C[r,n] = sum_k bf16(x[natural row r])[k]*Wb[n,k] + bias[n],
// stored to out row invg[r].
// KEY CHANGE vs v2b (134us, HBM 1.0 TB/s): the per-sample patch shuffle moved
// from the LOAD side (random 64B gather over 77MB -> ~1-2 TB/s wall) to the
// STORE side (row scatter, 3KB granularity, ~free). x is now streamed in
// natural order: dense sequential 64B segments, 896B contiguous runs, each
// line fetched once per XCD (6x L2 reuse via bijective swizzle).
// Pipeline (verified in v2b): B fragments reg-loaded from L2-resident Wb
// (1-iter prefetch, no global_load_lds -> no vmcnt(0) barrier drain);
// As double-buffered, ONE lgkm-only barrier/iter; x reg-prefetched 2 deep;
// LDS 16B-slot XOR involution on both ds_write and ds_read.
// ---------------------------------------------------------------------------
__global__ __launch_bounds__(256, 3)
void gemm_fused(const float* __restrict__ x, const int* __restrict__ invg,
                const unsigned short* __restrict__ Wb,
                const float* __restrict__ bias, float* __restrict__ out)
{
    __shared__ __align__(16) unsigned short As[2][BM * BK];  // 16 KB total

    const int tid = threadIdx.x;
    // XCD-bijective swizzle: 147 consecutive bm-major tiles per XCD.
    const int wg  = blockIdx.x;
    const int lid = (wg & 7) * CPX + (wg >> 3);
    const int bm  = lid / NBN;
    const int bn  = lid - bm * NBN;

    // ---- A staging coords: thread owns (row = tid>>1, 16-col seg = tid&1)
    const int arow = tid >> 1;
    const int aseg = tid & 1;
    const int gr   = bm * BM + arow;          // NATURAL row: sample b, patch p
    const int b    = gr / HWN;
    const int p    = gr - b * HWN;
    const int py   = p / 14, px = p - py * 14;
    const float* xbase = x + (size_t)b * 3 * IMG2
                           + (size_t)(py * 16) * IMGSZ + px * 16;
    const int axor  = ((arow >> 1) & 1) << 4;
    const int aoff0 = arow * 64 + ((aseg * 32     ) ^ axor);
    const int aoff1 = arow * 64 + ((aseg * 32 + 16) ^ axor);

    // ---- fragment coords
    const int lane = tid & 63;
    const int wave = tid >> 6;
    const int wm = (wave >> 1) * 64;
    const int wn = (wave & 1) * 64;
    const int lr = lane & 15;
    const int lq = lane >> 4;
    const int ard = (lq * 16) ^ (((lr >> 1) & 1) << 4);  // swizzled afrag k-byte

    // B fragment row pointers (L2-resident; full cache lines per load instr)
    const unsigned short* wrow0 = Wb + (size_t)(bn * BN + wn +  0 + lr) * KN + lq * 8;
    const unsigned short* wrow1 = Wb + (size_t)(bn * BN + wn + 16 + lr) * KN + lq * 8;
    const unsigned short* wrow2 = Wb + (size_t)(bn * BN + wn + 32 + lr) * KN + lq * 8;
    const unsigned short* wrow3 = Wb + (size_t)(bn * BN + wn + 48 + lr) * KN + lq * 8;

    floatx4 acc[4][4] = {};

    auto loadx = [&](int t) -> xs16 {
        const int s = t * 2 + aseg;               // 16-float seg id 0..47
        const float* src = xbase + (s >> 4) * IMG2 + (s & 15) * IMGSZ;
        xs16 r;
        r.a = *(const float4*)(src);
        r.b = *(const float4*)(src + 4);
        r.c = *(const float4*)(src + 8);
        r.d = *(const float4*)(src + 12);
        return r;
    };
    auto writea = [&](unsigned short* buf, const xs16& v) {
        *(bf16x8*)((char*)buf + aoff0) = cvt8v(v.a, v.b);
        *(bf16x8*)((char*)buf + aoff1) = cvt8v(v.c, v.d);
    };

    bf16x8 bfr0, bfr1, bfr2, bfr3;
    xs16 xq, xl;

    // ---- prologue: stage tile 0, prefetch tiles 1 & 2 (x) and tile 0 (B)
    xq = loadx(0);
    bfr0 = *(const bf16x8*)(wrow0);
    bfr1 = *(const bf16x8*)(wrow1);
    bfr2 = *(const bf16x8*)(wrow2);
    bfr3 = *(const bf16x8*)(wrow3);
    writea(As[0], xq);              // waits on xq only
    xq = loadx(1);
    xl = loadx(2);
    __syncthreads();                // As[0] visible (lgkm drain only)

    // One K-step. CUR/NXT are macro literals -> As indexing is fully static.
#define STEP(T, CUR, NXT)                                                     \
    do {                                                                      \
        const int t_ = (T);                                                   \
        if (t_ + 1 < NT) writea(As[NXT], xq);                                 \
        xq = xl;                                                              \
        if (t_ + 3 < NT) xl = loadx(t_ + 3);                                  \
        bf16x8 bnx0, bnx1, bnx2, bnx3;                                        \
        if (t_ + 1 < NT) {                                                    \
            bnx0 = *(const bf16x8*)(wrow0 + (t_ + 1) * BK);                   \
            bnx1 = *(const bf16x8*)(wrow1 + (t_ + 1) * BK);                   \
            bnx2 = *(const bf16x8*)(wrow2 + (t_ + 1) * BK);                   \
            bnx3 = *(const bf16x8*)(wrow3 + (t_ + 1) * BK);                   \
        }                                                                     \
        _Pragma("unroll")                                                     \
        for (int i = 0; i < 4; ++i) {                                         \
            const bf16x8 afrag = *(const bf16x8*)((const char*)As[CUR]        \
                                      + (wm + i * 16 + lr) * 64 + ard);       \
            acc[i][0] = __builtin_amdgcn_mfma_f32_16x16x32_bf16(afrag, bfr0, acc[i][0], 0, 0, 0); \
            acc[i][1] = __builtin_amdgcn_mfma_f32_16x16x32_bf16(afrag, bfr1, acc[i][1], 0, 0, 0); \
            acc[i][2] = __builtin_amdgcn_mfma_f32_16x16x32_bf16(afrag, bfr2, acc[i][2], 0, 0, 0); \
            acc[i][3] = __builtin_amdgcn_mfma_f32_16x16x32_bf16(afrag, bfr3, acc[i][3], 0, 0, 0); \
        }                                                                     \
        if (t_ + 1 < NT) {                                                    \
            bfr0 = bnx0; bfr1 = bnx1; bfr2 = bnx2; bfr3 = bnx3;               \
            __syncthreads();   /* As[CUR] reads done; As[NXT] visible */      \
        }                                                                     \
    } while (0)

    for (int tt = 0; tt < NT; tt += 2) {
        STEP(tt,     0, 1);
        STEP(tt + 1, 1, 0);
    }
#undef STEP

    // epilogue: destination rows via inverse-perm map (L2-hot, 512B/tile),
    // then bias + scattered-row store (C/D: col = lane&15, row = quad*4+reg).
    intx4 dr[4];
    #pragma unroll
    for (int i = 0; i < 4; ++i)
        dr[i] = *(const intx4*)&invg[bm * BM + wm + i * 16 + lq * 4];

    #pragma unroll
    for (int j = 0; j < 4; ++j) {
        const int gc = bn * BN + wn + j * 16 + lr;
        const float bv = bias[gc];
        #pragma unroll
        for (int i = 0; i < 4; ++i) {
            #pragma unroll
            for (int r = 0; r < 4; ++r)
                out[(size_t)dr[i][r] * HIDN + gc] = acc[i][j][r] + bv;
        }
    }
}

extern "C" void kernel_launch(void* const* d_in, const int* in_sizes, int n_in,
                              void* d_out, int out_size, void* d_ws, size_t ws_size,
                              hipStream_t stream) {
    const float* x    = (const float*)d_in[0];
    const float* W    = (const float*)d_in[1];
    const float* bias = (const float*)d_in[2];
    const int*   perm = (const int*)d_in[3];
    float* out = (float*)d_out;

    // workspace: Wb bf16 [768*768] (1.18 MB) + invg int [25088] (100 KB)
    unsigned short* Wb = (unsigned short*)d_ws;
    int* invg = (int*)((char*)d_ws + (size_t)KN * HIDN * sizeof(unsigned short));

    prep_W  <<<dim3(KN * HIDN / 8 / 256), dim3(256), 0, stream>>>(W, Wb);
    prep_inv<<<dim3(MTOT / 256),          dim3(256), 0, stream>>>(perm, invg);
    gemm_fused<<<dim3(NWG), dim3(256), 0, stream>>>(x, invg, Wb, bias, out);
}

// Round 5
// 182.263 us; speedup vs baseline: 1.2717x; 1.1976x over previous
//
#include <hip/hip_runtime.h>
#include <hip/hip_bf16.h>

// Problem constants
#define BATCH  128
#define HWN    196          // (224/16)^2 patches per sample
#define HIDN   768
#define KN     768          // 3*16*16
#define IMGSZ  224
#define IMG2   (224*224)
#define MTOT   (BATCH*HWN)  // 25088 rows

// GEMM tiling (round-0 verified m97 structure)
#define BM 128
#define BN 128
#define BK 32
#define NBM (MTOT/BM)       // 196
#define NBN (HIDN/BN)       // 6
#define NWG (NBM*NBN)       // 1176 = 8 * 147 -> bijective XCD swizzle
#define CPX (NWG/8)         // 147

typedef __attribute__((ext_vector_type(8))) short bf16x8;
typedef __attribute__((ext_vector_type(4))) float floatx4;

#define GP(p) ((const __attribute__((address_space(1))) void*)(p))
#define SP(p) ((__attribute__((address_space(3))) void*)(p))

static __device__ __forceinline__ short f2bf(float f) {
    __hip_bfloat16 h = __float2bfloat16(f);   // RNE
    return __builtin_bit_cast(short, h);
}

static __device__ __forceinline__ bf16x8 cvt8(const float* __restrict__ src) {
    float4 f0 = *(const float4*)(src);
    float4 f1 = *(const float4*)(src + 4);
    bf16x8 v;
    v[0]=f2bf(f0.x); v[1]=f2bf(f0.y); v[2]=f2bf(f0.z); v[3]=f2bf(f0.w);
    v[4]=f2bf(f1.x); v[5]=f2bf(f1.y); v[6]=f2bf(f1.z); v[7]=f2bf(f1.w);
    return v;
}

// ---------------------------------------------------------------------------
// prep_A (NATURAL order — no perm): A[gr, k] = bf16(x[b, c, patch gr pixel]),
// gr = b*196 + p (p natural), k = c*256 + iy*16 + ix. Pure streaming convert:
// reads are sequential 64 B chunks (adjacent patches complete each 128 B
// line), writes thread-contiguous 32 B. ~116 MB of traffic, no gather.
// The per-sample shuffle is applied later, at gemm staging time.
// ---------------------------------------------------------------------------
__global__ __launch_bounds__(256)
void prep_A(const float* __restrict__ x, unsigned short* __restrict__ A)
{
    const int idx = blockIdx.x * 256 + threadIdx.x;   // < 25088*48 (4704 blocks)
    const int gr  = idx / 48;
    const int seg = idx - gr * 48;                    // 0..47
    const int b   = gr / HWN;
    const int p   = gr - b * HWN;                     // natural patch index
    const int py  = p / 14, px = p - py * 14;
    const int c   = seg >> 4;                         // 0..2
    const int iy  = seg & 15;                         // 0..15

    const float* src = x + (size_t)b * 3 * IMG2 + (size_t)c * IMG2
                         + (size_t)(py * 16 + iy) * IMGSZ + px * 16;
    bf16x8 v0 = cvt8(src);
    bf16x8 v1 = cvt8(src + 8);
    unsigned short* dst = A + (size_t)gr * KN + seg * 16;
    *(bf16x8*)(dst)     = v0;
    *(bf16x8*)(dst + 8) = v1;
}

// ---------------------------------------------------------------------------
// prep_W: fp32 -> bf16, 768*768 elems, 8 per thread. 288 blocks of 256.
// ---------------------------------------------------------------------------
__global__ __launch_bounds__(256)
void prep_W(const float* __restrict__ W, unsigned short* __restrict__ Wb)
{
    const int idx = blockIdx.x * 256 + threadIdx.x;   // < 73728
    const float* src = W + (size_t)idx * 8;
    *(bf16x8*)(Wb + (size_t)idx * 8) = cvt8(src);
}

// ---------------------------------------------------------------------------
// gemm: out[gr, n] = sum_k A[b*196 + perm[gr], k] * Wb[n,k] + bias[n]
// EXACT round-0 structure (measured 62 us): glds width=16 staging, linear
// LDS, 2 barriers/iter, 4x4 acc/wave, contiguous epilogue. Two changes only:
//   1. the glds A source row is perm-indexed (glds takes per-lane source
//      addresses; A is L2/L3-resident with 24x temporal reuse per panel, so
//      the 64 B-granule randomness is absorbed by cache, unlike HBM x).
//   2. 1D grid + bijective XCD swizzle: the 6 bn-blocks of one bm-panel
//      land on one XCD -> A panel (192 KB) fetched ~once into its L2.
// ---------------------------------------------------------------------------
__global__ __launch_bounds__(256, 3)
void gemm(const unsigned short* __restrict__ A, const int* __restrict__ perm,
          const unsigned short* __restrict__ Wb,
          const float* __restrict__ bias, float* __restrict__ out)
{
    __shared__ __align__(16) unsigned short As[BM * BK];  // 8 KB
    __shared__ __align__(16) unsigned short Bs[BN * BK];  // 8 KB

    const int tid = threadIdx.x;
    const int wg  = blockIdx.x;
    const int lid = (wg & 7) * CPX + (wg >> 3);
    const int bm  = lid / NBN;
    const int bn  = lid - bm * NBN;

    // staging map: thread t stages 16 B of row (t>>2), k-seg (t&3).
    const int srow = tid >> 2;
    const int sseg = tid & 3;
    // perm-indexed A source rows (output row gr <- input patch perm[gr])
    const int gr0 = bm * BM + srow;        // rows 0..63 of tile
    const int gr1 = gr0 + 64;              // rows 64..127
    const int b0  = gr0 / HWN;
    const int b1  = gr1 / HWN;
    const int pr0 = b0 * HWN + perm[gr0];
    const int pr1 = b1 * HWN + perm[gr1];
    const unsigned short* ga0 = A  + (size_t)pr0 * KN + sseg * 8;
    const unsigned short* ga1 = A  + (size_t)pr1 * KN + sseg * 8;
    const unsigned short* gb  = Wb + (size_t)(bn * BN + srow) * KN + sseg * 8;

    // wave/fragment coords
    const int lane = tid & 63;
    const int wave = tid >> 6;
    const int wm = (wave >> 1) * 64;
    const int wn = (wave & 1) * 64;
    const int lr = lane & 15;
    const int lq = lane >> 4;

    floatx4 acc[4][4] = {};

    for (int k0 = 0; k0 < KN; k0 += BK) {
        __builtin_amdgcn_global_load_lds(GP(ga0 + k0),           SP(&As[tid * 8]),        16, 0, 0);
        __builtin_amdgcn_global_load_lds(GP(ga1 + k0),           SP(&As[2048 + tid * 8]), 16, 0, 0);
        __builtin_amdgcn_global_load_lds(GP(gb + k0),            SP(&Bs[tid * 8]),        16, 0, 0);
        __builtin_amdgcn_global_load_lds(GP(gb + 64 * KN + k0),  SP(&Bs[2048 + tid * 8]), 16, 0, 0);
        __syncthreads();

        bf16x8 bfrag[4];
        #pragma unroll
        for (int j = 0; j < 4; ++j)
            bfrag[j] = *(const bf16x8*)&Bs[(wn + j * 16 + lr) * BK + lq * 8];
        #pragma unroll
        for (int i = 0; i < 4; ++i) {
            bf16x8 afrag = *(const bf16x8*)&As[(wm + i * 16 + lr) * BK + lq * 8];
            #pragma unroll
            for (int j = 0; j < 4; ++j)
                acc[i][j] = __builtin_amdgcn_mfma_f32_16x16x32_bf16(
                                afrag, bfrag[j], acc[i][j], 0, 0, 0);
        }
        __syncthreads();
    }

    // epilogue: bias + contiguous store (C/D: col = lane&15, row = quad*4+reg)
    #pragma unroll
    for (int j = 0; j < 4; ++j) {
        const int gc = bn * BN + wn + j * 16 + lr;
        const float bv = bias[gc];
        #pragma unroll
        for (int i = 0; i < 4; ++i) {
            const int grow = bm * BM + wm + i * 16 + lq * 4;
            float* op = out + (size_t)grow * HIDN + gc;
            #pragma unroll
            for (int r = 0; r < 4; ++r)
                op[(size_t)r * HIDN] = acc[i][j][r] + bv;
        }
    }
}

extern "C" void kernel_launch(void* const* d_in, const int* in_sizes, int n_in,
                              void* d_out, int out_size, void* d_ws, size_t ws_size,
                              hipStream_t stream) {
    const float* x    = (const float*)d_in[0];
    const float* W    = (const float*)d_in[1];
    const float* bias = (const float*)d_in[2];
    const int*   perm = (const int*)d_in[3];
    float* out = (float*)d_out;

    // workspace layout (identical to round-0): A bf16 [25088*768] (38.5 MB),
    // Wb bf16 [768*768] (1.2 MB)
    unsigned short* A  = (unsigned short*)d_ws;
    unsigned short* Wb = A + (size_t)MTOT * KN;

    prep_A<<<dim3(MTOT * 48 / 256), dim3(256), 0, stream>>>(x, A);
    prep_W<<<dim3(KN * HIDN / 8 / 256), dim3(256), 0, stream>>>(W, Wb);
    gemm<<<dim3(NWG), dim3(256), 0, stream>>>(A, perm, Wb, bias, out);
}